// Round 1
// baseline (35726.578 us; speedup 1.0000x reference)
//
#include <hip/hip_runtime.h>
#include <cstddef>
#include <cstdint>

// Problem constants (CustomLSTM: T=512, B=64, I=1024, L=2, H=1024)
#define T_LEN   512
#define BATCH   64
#define IN_DIM  1024
#define HID     1024
#define GATES   4096   // 4*HID
#define NLAYERS 2
#define TCHUNK  64     // timesteps of xin staged per chunk (keeps ws ~193 MB)

// ---------------------------------------------------------------------------
// GEMM (NT): C[m][n] = sum_k A[m][k] * W[n][k] + bih[n] + bhh[n]
// A: M x 1024 row-major (M = TCHUNK*BATCH = 4096), W: 4096 x 1024 row-major.
// Tile 128x128, Kc=16, 256 threads, 8x8 micro-tile. fp32 FMA-bound:
// per kk: 4 ds_read_b128 (~32 cyc/wave) vs 64 v_fma_f32 (128 cyc/wave).
// ---------------------------------------------------------------------------
__global__ __launch_bounds__(256) void gemm_bias_nt(
    const float* __restrict__ A, const float* __restrict__ W,
    const float* __restrict__ bih, const float* __restrict__ bhh,
    float* __restrict__ C)
{
    const int K = IN_DIM;
    const int N = GATES;
    __shared__ float As[16][132];   // [k][m], +4 pad breaks store conflicts
    __shared__ float Ws[16][132];   // [k][n]

    const int m0 = blockIdx.y * 128;
    const int n0 = blockIdx.x * 128;
    const int tid = threadIdx.x;
    const int tx = tid & 15;        // -> 8 cols
    const int ty = tid >> 4;        // -> 8 rows
    const int lr = tid >> 2;        // 0..63 (load row; also +64)
    const int lc = (tid & 3) * 4;   // k offset 0/4/8/12

    float acc[8][8];
    #pragma unroll
    for (int i = 0; i < 8; ++i)
        #pragma unroll
        for (int j = 0; j < 8; ++j) acc[i][j] = 0.f;

    for (int k0 = 0; k0 < K; k0 += 16) {
        float4 a0 = *(const float4*)(A + (size_t)(m0 + lr)      * K + k0 + lc);
        float4 a1 = *(const float4*)(A + (size_t)(m0 + lr + 64) * K + k0 + lc);
        float4 w0 = *(const float4*)(W + (size_t)(n0 + lr)      * K + k0 + lc);
        float4 w1 = *(const float4*)(W + (size_t)(n0 + lr + 64) * K + k0 + lc);
        As[lc+0][lr] = a0.x; As[lc+1][lr] = a0.y; As[lc+2][lr] = a0.z; As[lc+3][lr] = a0.w;
        As[lc+0][lr+64] = a1.x; As[lc+1][lr+64] = a1.y; As[lc+2][lr+64] = a1.z; As[lc+3][lr+64] = a1.w;
        Ws[lc+0][lr] = w0.x; Ws[lc+1][lr] = w0.y; Ws[lc+2][lr] = w0.z; Ws[lc+3][lr] = w0.w;
        Ws[lc+0][lr+64] = w1.x; Ws[lc+1][lr+64] = w1.y; Ws[lc+2][lr+64] = w1.z; Ws[lc+3][lr+64] = w1.w;
        __syncthreads();
        #pragma unroll
        for (int kk = 0; kk < 16; ++kk) {
            float a[8], w[8];
            *(float4*)(a)     = *(const float4*)&As[kk][ty*8];
            *(float4*)(a + 4) = *(const float4*)&As[kk][ty*8 + 4];
            *(float4*)(w)     = *(const float4*)&Ws[kk][tx*8];
            *(float4*)(w + 4) = *(const float4*)&Ws[kk][tx*8 + 4];
            #pragma unroll
            for (int i = 0; i < 8; ++i)
                #pragma unroll
                for (int j = 0; j < 8; ++j)
                    acc[i][j] = fmaf(a[i], w[j], acc[i][j]);
        }
        __syncthreads();
    }

    float bj[8];
    #pragma unroll
    for (int j = 0; j < 8; ++j) {
        int n = n0 + tx*8 + j;
        bj[j] = bih[n] + bhh[n];
    }
    #pragma unroll
    for (int i = 0; i < 8; ++i) {
        size_t m = (size_t)(m0 + ty*8 + i);
        float* crow = C + m * N + n0 + tx*8;
        float4 o0, o1;
        o0.x = acc[i][0] + bj[0]; o0.y = acc[i][1] + bj[1];
        o0.z = acc[i][2] + bj[2]; o0.w = acc[i][3] + bj[3];
        o1.x = acc[i][4] + bj[4]; o1.y = acc[i][5] + bj[5];
        o1.z = acc[i][6] + bj[6]; o1.w = acc[i][7] + bj[7];
        *(float4*)(crow)     = o0;
        *(float4*)(crow + 4) = o1;
    }
}

// ---------------------------------------------------------------------------
// Recurrent step GEMM, split-K: gates[b][g] += sum_{k in slice} h[b][k]*wh[g][k]
// gates pre-initialized with xin (input proj + bias). Grid: (64 g-tiles, 4 K-
// splits) = 256 blocks = 1/CU. Tile 64x64, Kc=16, 256 threads, 4x4 micro.
// fp32 atomic adds (hardware global_atomic_add_f32 via unsafeAtomicAdd).
// ---------------------------------------------------------------------------
__global__ __launch_bounds__(256) void step_gemm(
    const float* __restrict__ h,    // [BATCH][HID]
    const float* __restrict__ wh,   // [GATES][HID]
    float* __restrict__ gates)      // [BATCH][GATES]
{
    __shared__ float Hs[16][68];
    __shared__ float Ws[16][68];
    const int g0 = blockIdx.x * 64;
    const int k0 = blockIdx.y * 256;
    const int tid = threadIdx.x;
    const int tx = tid & 15;
    const int ty = tid >> 4;
    const int lr = tid >> 2;        // 0..63
    const int lc = (tid & 3) * 4;

    float acc[4][4];
    #pragma unroll
    for (int i = 0; i < 4; ++i)
        #pragma unroll
        for (int j = 0; j < 4; ++j) acc[i][j] = 0.f;

    for (int kc = k0; kc < k0 + 256; kc += 16) {
        float4 hv = *(const float4*)(h  + (size_t)lr * HID + kc + lc);
        float4 wv = *(const float4*)(wh + (size_t)(g0 + lr) * HID + kc + lc);
        Hs[lc+0][lr] = hv.x; Hs[lc+1][lr] = hv.y; Hs[lc+2][lr] = hv.z; Hs[lc+3][lr] = hv.w;
        Ws[lc+0][lr] = wv.x; Ws[lc+1][lr] = wv.y; Ws[lc+2][lr] = wv.z; Ws[lc+3][lr] = wv.w;
        __syncthreads();
        #pragma unroll
        for (int kk = 0; kk < 16; ++kk) {
            float4 a = *(const float4*)&Hs[kk][ty*4];
            float4 w = *(const float4*)&Ws[kk][tx*4];
            float av[4] = {a.x, a.y, a.z, a.w};
            float wv2[4] = {w.x, w.y, w.z, w.w};
            #pragma unroll
            for (int i = 0; i < 4; ++i)
                #pragma unroll
                for (int j = 0; j < 4; ++j)
                    acc[i][j] = fmaf(av[i], wv2[j], acc[i][j]);
        }
        __syncthreads();
    }
    #pragma unroll
    for (int i = 0; i < 4; ++i) {
        int b = ty*4 + i;
        #pragma unroll
        for (int j = 0; j < 4; ++j) {
            int g = g0 + tx*4 + j;
            unsafeAtomicAdd(&gates[(size_t)b * GATES + g], acc[i][j]);
        }
    }
}

// ---------------------------------------------------------------------------
// Pointwise LSTM cell update. 65536 threads: idx -> (b, j).
// c' = sig(f)*c + sig(i)*tanh(g); h' = sig(o)*tanh(c'). Writes h, c, seq_out.
// ---------------------------------------------------------------------------
__global__ __launch_bounds__(256) void lstm_act(
    const float* __restrict__ gates,  // [BATCH][GATES]
    float* __restrict__ c,            // [BATCH][HID]
    float* __restrict__ h,            // [BATCH][HID]
    float* __restrict__ seq_out)      // [BATCH][HID] slice at t
{
    int idx = blockIdx.x * blockDim.x + threadIdx.x;  // 0..65535
    int b = idx >> 10;
    int j = idx & (HID - 1);
    const float* gr = gates + (size_t)b * GATES;
    float gi = gr[j];
    float gf = gr[j + HID];
    float gg = gr[j + 2*HID];
    float go = gr[j + 3*HID];
    float si = 1.f / (1.f + expf(-gi));
    float sf = 1.f / (1.f + expf(-gf));
    float so = 1.f / (1.f + expf(-go));
    float cn = sf * c[idx] + si * tanhf(gg);
    float hn = so * tanhf(cn);
    c[idx] = cn;
    h[idx] = hn;
    seq_out[idx] = hn;
}

// ---------------------------------------------------------------------------
extern "C" void kernel_launch(void* const* d_in, const int* in_sizes, int n_in,
                              void* d_out, int out_size, void* d_ws, size_t ws_size,
                              hipStream_t stream) {
    const float* x    = (const float*)d_in[0];  // [T,B,I]
    const float* w_ih = (const float*)d_in[1];  // [L,4H,I]
    const float* w_hh = (const float*)d_in[2];  // [L,4H,H]
    const float* b_ih = (const float*)d_in[3];  // [L,4H]
    const float* b_hh = (const float*)d_in[4];  // [L,4H]
    float* out = (float*)d_out;                 // seq | h_n | c_n

    // Workspace layout (floats):
    //   xin  : TCHUNK*B*4H = 16,777,216   (chunked input projection / gates)
    //   seq1 : T*B*H       = 33,554,432   (layer-0 output sequence)
    //   h, c : B*H each    (contiguous, zeroed per layer)
    // total ~193 MB
    float* xin  = (float*)d_ws;
    float* seq1 = xin + (size_t)TCHUNK * BATCH * GATES;
    float* hbuf = seq1 + (size_t)T_LEN * BATCH * HID;
    float* cbuf = hbuf + (size_t)BATCH * HID;

    const size_t seq_elems = (size_t)T_LEN * BATCH * HID;

    for (int l = 0; l < NLAYERS; ++l) {
        const float* in_seq = (l == 0) ? x : seq1;
        const float* wi = w_ih + (size_t)l * GATES * IN_DIM;
        const float* wh = w_hh + (size_t)l * GATES * HID;
        const float* bi = b_ih + (size_t)l * GATES;
        const float* bh = b_hh + (size_t)l * GATES;
        float* oseq = (l == 0) ? seq1 : out;

        hipMemsetAsync(hbuf, 0, 2 * (size_t)BATCH * HID * sizeof(float), stream);

        for (int ch = 0; ch < T_LEN / TCHUNK; ++ch) {
            const float* Ab = in_seq + (size_t)ch * TCHUNK * BATCH * IN_DIM;
            // xin[tt,b,g] = in @ wi^T + b  for this chunk (M=4096, N=4096, K=1024)
            gemm_bias_nt<<<dim3(GATES / 128, (TCHUNK * BATCH) / 128), 256, 0, stream>>>(
                Ab, wi, bi, bh, xin);
            for (int tt = 0; tt < TCHUNK; ++tt) {
                int t = ch * TCHUNK + tt;
                float* gates = xin + (size_t)tt * BATCH * GATES;
                step_gemm<<<dim3(GATES / 64, 4), 256, 0, stream>>>(hbuf, wh, gates);
                lstm_act<<<(BATCH * HID) / 256, 256, 0, stream>>>(
                    gates, cbuf, hbuf, oseq + (size_t)t * BATCH * HID);
            }
        }
        // h_n[l], c_n[l]
        hipMemcpyAsync(out + seq_elems + (size_t)l * BATCH * HID, hbuf,
                       (size_t)BATCH * HID * sizeof(float),
                       hipMemcpyDeviceToDevice, stream);
        hipMemcpyAsync(out + seq_elems + (size_t)(NLAYERS + l) * BATCH * HID, cbuf,
                       (size_t)BATCH * HID * sizeof(float),
                       hipMemcpyDeviceToDevice, stream);
    }
}

// Round 2
// 11716.077 us; speedup vs baseline: 3.0494x; 3.0494x over previous
//
#include <hip/hip_runtime.h>
#include <cstddef>
#include <cstdint>

// CustomLSTM: T=512, B=64, I=H=1024, L=2. fp32 in/out, bf16 MFMA internally.
#define T_LEN   512
#define BATCH   64
#define IN_DIM  1024
#define HID     1024
#define GATES   4096
#define NLAYERS 2
#define TCHUNK  64

typedef __bf16 bf16;
typedef __bf16 bf16x8 __attribute__((ext_vector_type(8)));
typedef float  f32x4  __attribute__((ext_vector_type(4)));

// ---------------------------------------------------------------------------
// fp32 -> bf16 (RNE), vectorized. n4 = n/4.
// ---------------------------------------------------------------------------
__global__ __launch_bounds__(256) void cvt_bf16(const float* __restrict__ in,
                                                bf16* __restrict__ out, int n4) {
    int i = blockIdx.x * blockDim.x + threadIdx.x;
    if (i >= n4) return;
    float4 v = ((const float4*)in)[i];
    bf16 o[4] = {(bf16)v.x, (bf16)v.y, (bf16)v.z, (bf16)v.w};
    *(uint2*)(out + 4 * (size_t)i) = *(uint2*)o;
}

// ---------------------------------------------------------------------------
// Input projection GEMM (NT, bf16 MFMA): C[m][n] = A[m][:]·W[n][:] + bias[n]
// M=TCHUNK*B=4096, N=GATES=4096, K=1024. 128x128 tile, BK=32, 256 thr, 4 waves
// each computing 64x64 as 4x4 grid of mfma_f32_16x16x32_bf16.
// AF32: A is fp32 (layer 0, converted during staging); else A is bf16.
// Verified layouts (learn_hip m89/m91): A-op lane l -> A[m=l&15][k=(l>>4)*8+j];
// D: row=(l>>4)*4+r, col=l&15.
// ---------------------------------------------------------------------------
template <bool AF32>
__global__ __launch_bounds__(256) void gemm_xin(
    const void* __restrict__ Aptr, const bf16* __restrict__ W,
    const float* __restrict__ bih, const float* __restrict__ bhh,
    float* __restrict__ C)
{
    __shared__ bf16 As[128 * 40];   // [m][k], pad 32->40 breaks b128 conflicts
    __shared__ bf16 Bs[128 * 40];   // [n][k]

    const int m0 = blockIdx.y * 128;
    const int n0 = blockIdx.x * 128;
    const int tid  = threadIdx.x;
    const int lane = tid & 63;
    const int wv   = tid >> 6;          // 0..3
    const int wm   = (wv & 1) * 64;
    const int wn   = (wv >> 1) * 64;
    const int quad = lane >> 4;         // 0..3
    const int l16  = lane & 15;

    f32x4 acc[4][4] = {};

    for (int k0 = 0; k0 < IN_DIM; k0 += 32) {
        if constexpr (AF32) {
            const float* A = (const float*)Aptr;
            const int row = tid >> 3;            // 0..31
            const int ko  = (tid & 7) * 4;       // 0..28
            #pragma unroll
            for (int p = 0; p < 4; ++p) {
                int r = row + 32 * p;
                float4 v = *(const float4*)(A + (size_t)(m0 + r) * IN_DIM + k0 + ko);
                bf16 o[4] = {(bf16)v.x, (bf16)v.y, (bf16)v.z, (bf16)v.w};
                *(uint2*)&As[r * 40 + ko] = *(uint2*)o;
            }
        } else {
            const bf16* A = (const bf16*)Aptr;
            const int row = tid >> 2;            // 0..63
            const int ko  = (tid & 3) * 8;       // 0,8,16,24
            *(uint4*)&As[row * 40 + ko] =
                *(const uint4*)(A + (size_t)(m0 + row) * IN_DIM + k0 + ko);
            *(uint4*)&As[(row + 64) * 40 + ko] =
                *(const uint4*)(A + (size_t)(m0 + row + 64) * IN_DIM + k0 + ko);
        }
        {
            const int row = tid >> 2;
            const int ko  = (tid & 3) * 8;
            *(uint4*)&Bs[row * 40 + ko] =
                *(const uint4*)(W + (size_t)(n0 + row) * IN_DIM + k0 + ko);
            *(uint4*)&Bs[(row + 64) * 40 + ko] =
                *(const uint4*)(W + (size_t)(n0 + row + 64) * IN_DIM + k0 + ko);
        }
        __syncthreads();

        bf16x8 af[4], bfr[4];
        #pragma unroll
        for (int t = 0; t < 4; ++t) {
            af[t]  = *(const bf16x8*)&As[(wm + t * 16 + l16) * 40 + quad * 8];
            bfr[t] = *(const bf16x8*)&Bs[(wn + t * 16 + l16) * 40 + quad * 8];
        }
        #pragma unroll
        for (int mt = 0; mt < 4; ++mt)
            #pragma unroll
            for (int nt = 0; nt < 4; ++nt)
                acc[mt][nt] = __builtin_amdgcn_mfma_f32_16x16x32_bf16(
                    af[mt], bfr[nt], acc[mt][nt], 0, 0, 0);
        __syncthreads();
    }

    #pragma unroll
    for (int nt = 0; nt < 4; ++nt) {
        int col = n0 + wn + nt * 16 + l16;
        float bias = bih[col] + bhh[col];
        #pragma unroll
        for (int mt = 0; mt < 4; ++mt) {
            #pragma unroll
            for (int r = 0; r < 4; ++r) {
                int row = m0 + wm + mt * 16 + quad * 4 + r;
                C[(size_t)row * GATES + col] = acc[mt][nt][r] + bias;
            }
        }
    }
}

// ---------------------------------------------------------------------------
// Fused recurrent step: gates = xin + h·wh^T, then activations; one launch/step.
// 256 blocks; block bk owns hidden units j0=4bk..+3 => gate rows type*1024+j0+u
// (all 4 gate types local => activation needs no cross-block traffic).
// 4 waves; wave w handles batches 16w..16w+15; MFMA 16x16 cols = (type*4+u).
// wh slice (16 rows x 1024) staged in LDS (coalesced, shared by 4 waves).
// h is ping-pong bf16 (h_in != h_out: blocks race otherwise). c is fp32,
// touched only by the owning thread (read->write same kernel is safe).
// ---------------------------------------------------------------------------
__global__ __launch_bounds__(256) void lstm_step(
    const bf16*  __restrict__ h_in,    // [B][H] bf16
    const bf16*  __restrict__ wh,      // [4H][H] bf16
    const float* __restrict__ xg,      // [B][4H] fp32 (xin slice for this t)
    float*       __restrict__ cbuf,    // [B][H]
    float*       __restrict__ hf32,    // [B][H] (for h_n copy-out)
    bf16*        __restrict__ h_out,   // [B][H] bf16
    bf16*        __restrict__ seq_bf,  // [B][H] slice, or null (layer 0)
    float*       __restrict__ seq_f32) // [B][H] slice, or null (layer 1)
{
    __shared__ bf16  Bs[16 * 1032];    // wh slice [16 rows][1024], pad->1032
    __shared__ float sg[4 * 256];      // per-wave 16x16 gate tile

    const int bk   = blockIdx.x;
    const int j0   = bk * 4;
    const int tid  = threadIdx.x;
    const int lane = tid & 63;
    const int wv   = tid >> 6;
    const int m0   = wv * 16;          // batch base for this wave
    const int quad = lane >> 4;
    const int l16  = lane & 15;

    // stage wh rows: row = type*4+u  ->  gate row type*1024 + j0 + u
    #pragma unroll
    for (int i = 0; i < 8; ++i) {
        int flat = i * 256 + tid;       // 0..2047 (16 rows x 128 uint4)
        int row  = flat >> 7;
        int k16  = flat & 127;
        int grr  = (row >> 2) * 1024 + j0 + (row & 3);
        *(uint4*)&Bs[row * 1032 + k16 * 8] =
            *(const uint4*)(wh + (size_t)grr * HID + k16 * 8);
    }

    // C init from xin (gates pre-add): D layout row=quad*4+r (batch), col=l16
    const int type = l16 >> 2, u = l16 & 3;
    const int gr = type * 1024 + j0 + u;
    f32x4 acc;
    #pragma unroll
    for (int r = 0; r < 4; ++r)
        acc[r] = xg[(size_t)(m0 + quad * 4 + r) * GATES + gr];

    __syncthreads();

    const bf16* aptr = h_in + (size_t)(m0 + l16) * HID + quad * 8;
    const bf16* bptr = &Bs[l16 * 1032 + quad * 8];
    #pragma unroll 4
    for (int k0 = 0; k0 < HID; k0 += 32) {
        bf16x8 a = *(const bf16x8*)(aptr + k0);
        bf16x8 b = *(const bf16x8*)(bptr + k0);
        acc = __builtin_amdgcn_mfma_f32_16x16x32_bf16(a, b, acc, 0, 0, 0);
    }

    // gate exchange within wave via LDS
    #pragma unroll
    for (int r = 0; r < 4; ++r)
        sg[wv * 256 + (quad * 4 + r) * 16 + l16] = acc[r];
    __syncthreads();

    // activation: lane -> (batch = m0+l16, unit = quad)
    {
        int bb = m0 + l16;
        int uu = quad;
        const float* g = &sg[wv * 256 + l16 * 16];
        float gi = g[uu], gf = g[4 + uu], gg = g[8 + uu], go = g[12 + uu];
        float si = 1.f / (1.f + expf(-gi));
        float sf = 1.f / (1.f + expf(-gf));
        float so = 1.f / (1.f + expf(-go));
        int idx = bb * HID + j0 + uu;
        float cv = sf * cbuf[idx] + si * tanhf(gg);
        float hv = so * tanhf(cv);
        cbuf[idx] = cv;
        hf32[idx] = hv;
        h_out[idx] = (bf16)hv;
        if (seq_bf)  seq_bf[idx]  = (bf16)hv;
        if (seq_f32) seq_f32[idx] = hv;
    }
}

// ---------------------------------------------------------------------------
extern "C" void kernel_launch(void* const* d_in, const int* in_sizes, int n_in,
                              void* d_out, int out_size, void* d_ws, size_t ws_size,
                              hipStream_t stream) {
    const float* x    = (const float*)d_in[0];
    const float* w_ih = (const float*)d_in[1];
    const float* w_hh = (const float*)d_in[2];
    const float* b_ih = (const float*)d_in[3];
    const float* b_hh = (const float*)d_in[4];
    float* out = (float*)d_out;

    // ws layout (fp32 region first for alignment):
    //   xin    : TCHUNK*B*4H fp32 = 64 MB
    //   cbuf   : B*H fp32, hf32: B*H fp32
    //   seq1bf : T*B*H bf16 = 64 MB   (layer-0 output, layer-1 GEMM input)
    //   wibf   : 4H*I bf16 (per-layer reuse), whbf: 4H*H bf16
    //   hping  : 2 * B*H bf16
    float* xin  = (float*)d_ws;
    float* cbuf = xin + (size_t)TCHUNK * BATCH * GATES;
    float* hf32 = cbuf + (size_t)BATCH * HID;
    bf16* seq1bf = (bf16*)(hf32 + (size_t)BATCH * HID);
    bf16* wibf   = seq1bf + (size_t)T_LEN * BATCH * HID;
    bf16* whbf   = wibf + (size_t)GATES * IN_DIM;
    bf16* hping  = whbf + (size_t)GATES * HID;

    const size_t seqE = (size_t)T_LEN * BATCH * HID;
    const size_t BH   = (size_t)BATCH * HID;

    for (int l = 0; l < NLAYERS; ++l) {
        const float* wi = w_ih + (size_t)l * GATES * IN_DIM;
        const float* wh = w_hh + (size_t)l * GATES * HID;
        const float* bi = b_ih + (size_t)l * GATES;
        const float* bh = b_hh + (size_t)l * GATES;

        // weights -> bf16 (per-layer buffers, reused across layers)
        cvt_bf16<<<(GATES * IN_DIM / 4 + 255) / 256, 256, 0, stream>>>(wi, wibf, GATES * IN_DIM / 4);
        cvt_bf16<<<(GATES * HID / 4 + 255) / 256, 256, 0, stream>>>(wh, whbf, GATES * HID / 4);

        hipMemsetAsync(hping, 0, BH * sizeof(bf16), stream);       // h(-1)=0
        hipMemsetAsync(cbuf, 0, BH * sizeof(float), stream);       // c(-1)=0

        for (int ch = 0; ch < T_LEN / TCHUNK; ++ch) {
            // input projection for this chunk: [4096 x 4096 x 1024]
            if (l == 0) {
                const float* Ab = x + (size_t)ch * TCHUNK * BATCH * IN_DIM;
                gemm_xin<true><<<dim3(GATES / 128, TCHUNK * BATCH / 128), 256, 0, stream>>>(
                    Ab, wibf, bi, bh, xin);
            } else {
                const bf16* Ab = seq1bf + (size_t)ch * TCHUNK * BATCH * HID;
                gemm_xin<false><<<dim3(GATES / 128, TCHUNK * BATCH / 128), 256, 0, stream>>>(
                    Ab, wibf, bi, bh, xin);
            }
            for (int tt = 0; tt < TCHUNK; ++tt) {
                int t = ch * TCHUNK + tt;
                const bf16* hi = hping + (size_t)(t & 1) * BH;
                bf16* ho = hping + (size_t)(1 - (t & 1)) * BH;
                bf16* sb  = (l == 0) ? (seq1bf + (size_t)t * BH) : nullptr;
                float* sf = (l == 1) ? (out + (size_t)t * BH) : nullptr;
                lstm_step<<<256, 256, 0, stream>>>(
                    hi, whbf, xin + (size_t)tt * BATCH * GATES,
                    cbuf, hf32, ho, sb, sf);
            }
        }
        hipMemcpyAsync(out + seqE + (size_t)l * BH, hf32, BH * sizeof(float),
                       hipMemcpyDeviceToDevice, stream);
        hipMemcpyAsync(out + seqE + (size_t)(NLAYERS + l) * BH, cbuf, BH * sizeof(float),
                       hipMemcpyDeviceToDevice, stream);
    }
}